// Round 5
// baseline (316.497 us; speedup 1.0000x reference)
//
#include <hip/hip_runtime.h>

#define WW 1024
#define HH 1024
#define NIMG 2
#define NCH 8
#define HWSZ (HH * WW)
#define CHW (NCH * HWSZ)
#define NBLK_MAIN 2048
// ws u32 layout: [0..2047] block mins, [2048..4095] block maxs,
// [4096] sum, [4097] cnt, [4098] ticket,
// dv16 (packed unorm16 mask diff) at 4352, u8 qt records at WS_QT.
#define WS_SUM 4096
#define WS_CNT 4097
#define WS_TKT 4098
#define WS_DV16 4352
#define WS_QT (4352 + HWSZ)
#define RECU4 320   // uint4 per (n,row,half) record: [p0 136][p1 136][pad 48]

typedef unsigned int uint;

__device__ __forceinline__ uint pknorm(float a, float b) {
    uint d;
    asm("v_cvt_pknorm_u16_f32 %0, %1, %2" : "=v"(d) : "v"(a), "v"(b));
    return d;
}
__device__ __forceinline__ uint sadu8(uint a, uint b, uint c) {
    uint d;
    asm("v_sad_u8 %0, %1, %2, %3" : "=v"(d) : "v"(a), "v"(b), "v"(c));
    return d;
}
__device__ __forceinline__ uint q8(float x) {
    return (uint)__float2int_rn(x * 255.f);
}
__device__ __forceinline__ int reflect_idx(int t) {
    if (t < 0) t = -t;
    if (t > HH - 1) t = 2 * (HH - 1) - t;
    return t;
}
// padded granule (0..135) -> E/O slot (E first, then O)
__device__ __forceinline__ int gp2slot(int gp) {
    return (gp & 1) ? (68 + (gp >> 1)) : (gp >> 1);
}

// Fused pass 0+1 (verified in R4, unchanged).
// b3 % 3 in {0,1} -> quant block qb = (b3/3)*2 + (b3%3)   (4096 blocks)
// b3 % 3 == 2     -> mask block  mb = b3/3                (2048 blocks)
__global__ __launch_bounds__(256) void k_pre(const float* __restrict__ tgt,
                                             uint4* __restrict__ qt4,
                                             const float* __restrict__ msO,
                                             const float* __restrict__ pan,
                                             float* __restrict__ wsF,
                                             uint* __restrict__ dv16) {
    const int b3 = blockIdx.x;
    const int m3 = b3 % 3;
    const int t = threadIdx.x;

    if (m3 != 2) {
        // ---------------- quant body ----------------
        int b = (b3 / 3) * 2 + m3;     // (n*2+p)*1024 + row
        int row = b & 1023;
        int np = b >> 10;
        int n = np >> 1, p = np & 1;
        const float* c0 = tgt + (size_t)(n * NCH + 4 * p) * HWSZ + (size_t)row * WW;

        float4 v0 = *(const float4*)(c0 + 4 * t);
        float4 v1 = *(const float4*)(c0 + HWSZ + 4 * t);
        float4 v2 = *(const float4*)(c0 + 2 * HWSZ + 4 * t);
        float4 v3 = *(const float4*)(c0 + 3 * HWSZ + 4 * t);
        uint4 u;
        u.x = q8(v0.x) | (q8(v1.x) << 8) | (q8(v2.x) << 16) | (q8(v3.x) << 24);
        u.y = q8(v0.y) | (q8(v1.y) << 8) | (q8(v2.y) << 16) | (q8(v3.y) << 24);
        u.z = q8(v0.z) | (q8(v1.z) << 8) | (q8(v2.z) << 16) | (q8(v3.z) << 24);
        u.w = q8(v0.w) | (q8(v1.w) << 8) | (q8(v2.w) << 16) | (q8(v3.w) << 24);

        size_t rb = ((size_t)((n << 10) + row)) * 2;
        int h1 = t >> 7;
        int gp = (t & 127) + 4;        // 4..131 within own half
        qt4[(rb + h1) * RECU4 + p * 136 + gp2slot(gp)] = u;
        // interior overlap granules (appear in the other half's halo region)
        if (t >= 124 && t < 128)
            qt4[(rb + 1) * RECU4 + p * 136 + gp2slot(t - 124)] = u;
        if (t >= 128 && t < 132)
            qt4[(rb + 0) * RECU4 + p * 136 + gp2slot(t - 128 + 132)] = u;
        // reflected edge halos: 32 scalar u32 (one px each)
        if (t < 32) {
            int which = t >> 4, m = t & 15;
            int pc = which ? (528 + m) : m;          // padded col
            int j = which ? (1022 - m) : (16 - m);   // reflected image col
            uint val = q8(c0[j]) | (q8(c0[j + HWSZ]) << 8) |
                       (q8(c0[j + 2 * HWSZ]) << 16) | (q8(c0[j + 3 * HWSZ]) << 24);
            uint* recU = (uint*)(qt4 + (rb + which) * RECU4);
            recU[p * 544 + gp2slot(pc >> 2) * 4 + (pc & 3)] = val;
        }
    } else {
        // ---------------- mask body ----------------
        int b = b3 / 3;
        int gid = b * 256 + t;
        int base = gid * 4;
        int n = base >> 20;
        int hw = base & (HWSZ - 1);
        const float* po = msO + (size_t)n * CHW + hw;
        float sx = 0.f, sy = 0.f, sz = 0.f, sw = 0.f;
#pragma unroll
        for (int c = 0; c < NCH; ++c) {
            float4 v = *(const float4*)(po + c * HWSZ);
            sx += v.x; sy += v.y; sz += v.z; sw += v.w;
        }
        float4 pv = *(const float4*)(pan + (size_t)n * HWSZ + hw);
        float4 d;
        d.x = fabsf(sx * 0.125f - pv.x);
        d.y = fabsf(sy * 0.125f - pv.y);
        d.z = fabsf(sz * 0.125f - pv.z);
        d.w = fabsf(sw * 0.125f - pv.w);
        uint2 dpk;
        dpk.x = pknorm(d.x, d.y);
        dpk.y = pknorm(d.z, d.w);
        *(uint2*)(dv16 + (base >> 1)) = dpk;

        float m = fminf(fminf(d.x, d.y), fminf(d.z, d.w));
        float M = fmaxf(fmaxf(d.x, d.y), fmaxf(d.z, d.w));
#pragma unroll
        for (int off = 32; off > 0; off >>= 1) {
            m = fminf(m, __shfl_down(m, off));
            M = fmaxf(M, __shfl_down(M, off));
        }
        __shared__ float sm[4], sM[4];
        int wid = t >> 6, lane = t & 63;
        if (lane == 0) { sm[wid] = m; sM[wid] = M; }
        __syncthreads();
        if (t == 0) {
            wsF[b] = fminf(fminf(sm[0], sm[1]), fminf(sm[2], sm[3]));
            wsF[2048 + b] = fmaxf(fmaxf(sM[0], sM[1]), fmaxf(sM[2], sM[3]));
            if (b == 0) {
                wsF[WS_SUM] = 0.f;
                wsF[WS_CNT] = 0.f;
                ((unsigned*)wsF)[WS_TKT] = 0u;
            }
        }
    }
}

// Pass 2: one 256-thread block = one full output row; each lane owns ONE granule
// (4 px x 8 ch). Because S_STRIDE=4 every shift is granule-aligned, so each
// (di,dj) step needs exactly ONE uint4 per plane, read directly from qt4 (L2).
// Live set ~45 VGPR -> compatible with the backend's 8-wave/64-reg heuristic
// (R2's burst design serialized at that budget; this one doesn't need ILP).
// Grid 2048 = 8 blocks/CU exactly: full occupancy, no tail, no LDS staging.
__global__ __launch_bounds__(256) void k_main(const float* __restrict__ ms,
                                              const uint4* __restrict__ qt4,
                                              float* __restrict__ wsF,
                                              const uint* __restrict__ dv16,
                                              float* __restrict__ out) {
    const int tid = threadIdx.x;      // 0..255 = granule within row
    const int lane = tid & 63;
    const int wid = tid >> 6;
    const int b = blockIdx.x;         // 0..2047
    const int xcd = b & 7;
    const int idx = b >> 3;           // 0..255
    const int n = idx >> 7;
    const int row = xcd * 128 + (idx & 127);
    const int hb = tid >> 7;          // column half
    const int g = tid & 127;          // granule within half

    // ---- mask min/max over the 2048 block-mins/maxs ----
    float lmin = 1.0e38f, lmax = -1.0e38f;
#pragma unroll
    for (int k = 0; k < 2; ++k) {
        float4 v = ((const float4*)wsF)[k * 256 + tid];
        float4 x = ((const float4*)(wsF + 2048))[k * 256 + tid];
        lmin = fminf(lmin, fminf(fminf(v.x, v.y), fminf(v.z, v.w)));
        lmax = fmaxf(lmax, fmaxf(fmaxf(x.x, x.y), fmaxf(x.z, x.w)));
    }
#pragma unroll
    for (int off = 32; off > 0; off >>= 1) {
        lmin = fminf(lmin, __shfl_xor(lmin, off));
        lmax = fmaxf(lmax, __shfl_xor(lmax, off));
    }
    __shared__ float sMn[4], sMx[4], sS[4], sC[4];
    if (lane == 0) { sMn[wid] = lmin; sMx[wid] = lmax; }
    __syncthreads();
    lmin = fminf(fminf(sMn[0], sMn[1]), fminf(sMn[2], sMn[3]));
    lmax = fmaxf(fmaxf(sMx[0], sMx[1]), fmaxf(sMx[2], sMx[3]));
    const float thresh = lmin + (lmax - lmin) * (10.0f / 255.0f);
    const float inv16 = 1.0f / 65535.0f;
    const float inv8 = 1.0f / 255.0f;

    // ---- ms fragment: 4 px x 8 ch -> msq[2][4], loaded in two p-phases ----
    const float* msBase = ms + (size_t)n * CHW + (size_t)row * WW + 4 * tid;
    uint msq[2][4];
#pragma unroll
    for (int p = 0; p < 2; ++p) {
        float4 c0 = *(const float4*)(msBase + (size_t)(4 * p + 0) * HWSZ);
        float4 c1 = *(const float4*)(msBase + (size_t)(4 * p + 1) * HWSZ);
        float4 c2 = *(const float4*)(msBase + (size_t)(4 * p + 2) * HWSZ);
        float4 c3 = *(const float4*)(msBase + (size_t)(4 * p + 3) * HWSZ);
        msq[p][0] = q8(c0.x) | (q8(c1.x) << 8) | (q8(c2.x) << 16) | (q8(c3.x) << 24);
        msq[p][1] = q8(c0.y) | (q8(c1.y) << 8) | (q8(c2.y) << 16) | (q8(c3.y) << 24);
        msq[p][2] = q8(c0.z) | (q8(c1.z) << 8) | (q8(c2.z) << 16) | (q8(c3.z) << 24);
        msq[p][3] = q8(c0.w) | (q8(c1.w) << 8) | (q8(c2.w) << 16) | (q8(c3.w) << 24);
    }

    uint minv[4] = {0xffffffffu, 0xffffffffu, 0xffffffffu, 0xffffffffu};
    const size_t nBase = ((size_t)n << 10);
    // even-dj walk starts at slot of granule g, odd-dj walk at granule g+1;
    // both advance +1 slot per 2 dj for either parity of g.
    const int sA = gp2slot(g);
    const int sB = gp2slot(g + 1);

#pragma unroll 1
    for (int di = 0; di < 9; ++di) {
        int rr = reflect_idx(row + 4 * (di - 4));   // wave-uniform (SGPR)
        const uint4* rec4 = qt4 + ((nBase + rr) * 2 + hb) * RECU4;
        const uint4* rA0 = rec4 + sA;
        const uint4* rB0 = rec4 + sB;
        const uint4* rA1 = rec4 + 136 + sA;
        const uint4* rB1 = rec4 + 136 + sB;
#pragma unroll
        for (int dj = 0; dj < 9; ++dj) {
            uint4 g0 = (dj & 1) ? rB0[(dj - 1) >> 1] : rA0[dj >> 1];
            uint4 g1 = (dj & 1) ? rB1[(dj - 1) >> 1] : rA1[dj >> 1];
            uint a0 = sadu8(msq[0][0], g0.x, 0u); a0 = sadu8(msq[1][0], g1.x, a0);
            uint a1 = sadu8(msq[0][1], g0.y, 0u); a1 = sadu8(msq[1][1], g1.y, a1);
            uint a2 = sadu8(msq[0][2], g0.z, 0u); a2 = sadu8(msq[1][2], g1.z, a2);
            uint a3 = sadu8(msq[0][3], g0.w, 0u); a3 = sadu8(msq[1][3], g1.w, a3);
            minv[0] = min(minv[0], a0);
            minv[1] = min(minv[1], a1);
            minv[2] = min(minv[2], a2);
            minv[3] = min(minv[3], a3);
        }
    }

    // ---- masked accumulate (dq loaded late to keep it out of hot live range) ----
    uint2 dq = *(const uint2*)(dv16 + (((size_t)n * HWSZ + (size_t)row * WW + 4 * tid) >> 1));
    float lsum = 0.f, lcnt = 0.f;
    {
        float d0 = (float)(dq.x & 0xffffu) * inv16;
        float d1 = (float)(dq.x >> 16) * inv16;
        float d2 = (float)(dq.y & 0xffffu) * inv16;
        float d3 = (float)(dq.y >> 16) * inv16;
        if (d0 > thresh) { lsum += (float)minv[0] * inv8; lcnt += 1.f; }
        if (d1 > thresh) { lsum += (float)minv[1] * inv8; lcnt += 1.f; }
        if (d2 > thresh) { lsum += (float)minv[2] * inv8; lcnt += 1.f; }
        if (d3 > thresh) { lsum += (float)minv[3] * inv8; lcnt += 1.f; }
    }

#pragma unroll
    for (int off = 32; off > 0; off >>= 1) {
        lsum += __shfl_down(lsum, off);
        lcnt += __shfl_down(lcnt, off);
    }
    if (lane == 0) { sS[wid] = lsum; sC[wid] = lcnt; }
    __syncthreads();
    if (tid == 0) {
        float bs = sS[0] + sS[1] + sS[2] + sS[3];
        float bc = sC[0] + sC[1] + sC[2] + sC[3];
        atomicAdd(&wsF[WS_SUM], bs);
        atomicAdd(&wsF[WS_CNT], bc);
        __threadfence();
        unsigned tk = atomicAdd((unsigned*)&wsF[WS_TKT], 1u);
        if (tk == NBLK_MAIN - 1) {
            float s = atomicAdd(&wsF[WS_SUM], 0.f);
            float c = atomicAdd(&wsF[WS_CNT], 0.f);
            out[0] = (c > 0.f) ? (s / fmaxf(c, 1.f)) : 0.f;
        }
    }
}

extern "C" void kernel_launch(void* const* d_in, const int* in_sizes, int n_in,
                              void* d_out, int out_size, void* d_ws, size_t ws_size,
                              hipStream_t stream) {
    const float* ms  = (const float*)d_in[0];
    const float* tgt = (const float*)d_in[1];
    const float* msO = (const float*)d_in[2];
    const float* pan = (const float*)d_in[3];
    float* out = (float*)d_out;
    float* wsF = (float*)d_ws;
    uint* dv16 = (uint*)d_ws + WS_DV16;
    uint4* qt4 = (uint4*)((uint*)d_ws + WS_QT);

    k_pre<<<6144, 256, 0, stream>>>(tgt, qt4, msO, pan, wsF, dv16);
    k_main<<<NBLK_MAIN, 256, 0, stream>>>(ms, qt4, wsF, dv16, out);
}

// Round 6
// 258.545 us; speedup vs baseline: 1.2241x; 1.2241x over previous
//
#include <hip/hip_runtime.h>

#define WW 1024
#define HH 1024
#define NIMG 2
#define NCH 8
#define HWSZ (HH * WW)
#define CHW (NCH * HWSZ)
#define NBLK_MAIN 1024
// ws u32 layout: [0..2047] block mins, [2048..4095] block maxs,
// [4096] sum, [4097] cnt, [4098] ticket,
// dv16 (packed unorm16 mask diff) at 4352, u8 qt records at WS_QT.
#define WS_SUM 4096
#define WS_CNT 4097
#define WS_TKT 4098
#define WS_DV16 4352
#define WS_QT (4352 + HWSZ)
#define RECU4 320   // uint4 per (n,row,half) GLOBAL record: [p0 136][p1 136][pad 48]
#define SLOTC 1088  // u32 per compact LDS slot (4352 B used; pad NOT staged)
#define NSLOT 12    // rows h0-16 .. h0+28, step 4 (covers k=0..3, di=0..8)

typedef unsigned int uint;

__device__ __forceinline__ uint pknorm(float a, float b) {
    uint d;
    asm("v_cvt_pknorm_u16_f32 %0, %1, %2" : "=v"(d) : "v"(a), "v"(b));
    return d;
}
__device__ __forceinline__ uint sadu8(uint a, uint b, uint c) {
    uint d;
    asm("v_sad_u8 %0, %1, %2, %3" : "=v"(d) : "v"(a), "v"(b), "v"(c));
    return d;
}
__device__ __forceinline__ uint q8(float x) {
    return (uint)__float2int_rn(x * 255.f);
}
__device__ __forceinline__ int reflect_idx(int t) {
    if (t < 0) t = -t;
    if (t > HH - 1) t = 2 * (HH - 1) - t;
    return t;
}
// padded granule (0..135) -> E/O slot (E first, then O)
__device__ __forceinline__ int gp2slot(int gp) {
    return (gp & 1) ? (68 + (gp >> 1)) : (gp >> 1);
}

#define GLD16(g, l)                                                         \
    __builtin_amdgcn_global_load_lds(                                       \
        (const __attribute__((address_space(1))) uint*)(g),                 \
        (__attribute__((address_space(3))) uint*)(l), 16, 0, 0)

// Fused pass 0+1 (verified R4/R5, unchanged).
// b3 % 3 in {0,1} -> quant block qb = (b3/3)*2 + (b3%3)   (4096 blocks)
// b3 % 3 == 2     -> mask block  mb = b3/3                (2048 blocks)
__global__ __launch_bounds__(256) void k_pre(const float* __restrict__ tgt,
                                             uint4* __restrict__ qt4,
                                             const float* __restrict__ msO,
                                             const float* __restrict__ pan,
                                             float* __restrict__ wsF,
                                             uint* __restrict__ dv16) {
    const int b3 = blockIdx.x;
    const int m3 = b3 % 3;
    const int t = threadIdx.x;

    if (m3 != 2) {
        // ---------------- quant body ----------------
        int b = (b3 / 3) * 2 + m3;     // (n*2+p)*1024 + row
        int row = b & 1023;
        int np = b >> 10;
        int n = np >> 1, p = np & 1;
        const float* c0 = tgt + (size_t)(n * NCH + 4 * p) * HWSZ + (size_t)row * WW;

        float4 v0 = *(const float4*)(c0 + 4 * t);
        float4 v1 = *(const float4*)(c0 + HWSZ + 4 * t);
        float4 v2 = *(const float4*)(c0 + 2 * HWSZ + 4 * t);
        float4 v3 = *(const float4*)(c0 + 3 * HWSZ + 4 * t);
        uint4 u;
        u.x = q8(v0.x) | (q8(v1.x) << 8) | (q8(v2.x) << 16) | (q8(v3.x) << 24);
        u.y = q8(v0.y) | (q8(v1.y) << 8) | (q8(v2.y) << 16) | (q8(v3.y) << 24);
        u.z = q8(v0.z) | (q8(v1.z) << 8) | (q8(v2.z) << 16) | (q8(v3.z) << 24);
        u.w = q8(v0.w) | (q8(v1.w) << 8) | (q8(v2.w) << 16) | (q8(v3.w) << 24);

        size_t rb = ((size_t)((n << 10) + row)) * 2;
        int h1 = t >> 7;
        int gp = (t & 127) + 4;        // 4..131 within own half
        qt4[(rb + h1) * RECU4 + p * 136 + gp2slot(gp)] = u;
        // interior overlap granules (appear in the other half's halo region)
        if (t >= 124 && t < 128)
            qt4[(rb + 1) * RECU4 + p * 136 + gp2slot(t - 124)] = u;
        if (t >= 128 && t < 132)
            qt4[(rb + 0) * RECU4 + p * 136 + gp2slot(t - 128 + 132)] = u;
        // reflected edge halos: 32 scalar u32 (one px each)
        if (t < 32) {
            int which = t >> 4, m = t & 15;
            int pc = which ? (528 + m) : m;          // padded col
            int j = which ? (1022 - m) : (16 - m);   // reflected image col
            uint val = q8(c0[j]) | (q8(c0[j + HWSZ]) << 8) |
                       (q8(c0[j + 2 * HWSZ]) << 16) | (q8(c0[j + 3 * HWSZ]) << 24);
            uint* recU = (uint*)(qt4 + (rb + which) * RECU4);
            recU[p * 544 + gp2slot(pc >> 2) * 4 + (pc & 3)] = val;
        }
    } else {
        // ---------------- mask body ----------------
        int b = b3 / 3;
        int gid = b * 256 + t;
        int base = gid * 4;
        int n = base >> 20;
        int hw = base & (HWSZ - 1);
        const float* po = msO + (size_t)n * CHW + hw;
        float sx = 0.f, sy = 0.f, sz = 0.f, sw = 0.f;
#pragma unroll
        for (int c = 0; c < NCH; ++c) {
            float4 v = *(const float4*)(po + c * HWSZ);
            sx += v.x; sy += v.y; sz += v.z; sw += v.w;
        }
        float4 pv = *(const float4*)(pan + (size_t)n * HWSZ + hw);
        float4 d;
        d.x = fabsf(sx * 0.125f - pv.x);
        d.y = fabsf(sy * 0.125f - pv.y);
        d.z = fabsf(sz * 0.125f - pv.z);
        d.w = fabsf(sw * 0.125f - pv.w);
        uint2 dpk;
        dpk.x = pknorm(d.x, d.y);
        dpk.y = pknorm(d.z, d.w);
        *(uint2*)(dv16 + (base >> 1)) = dpk;

        float m = fminf(fminf(d.x, d.y), fminf(d.z, d.w));
        float M = fmaxf(fmaxf(d.x, d.y), fmaxf(d.z, d.w));
#pragma unroll
        for (int off = 32; off > 0; off >>= 1) {
            m = fminf(m, __shfl_down(m, off));
            M = fmaxf(M, __shfl_down(M, off));
        }
        __shared__ float sm[4], sM[4];
        int wid = t >> 6, lane = t & 63;
        if (lane == 0) { sm[wid] = m; sM[wid] = M; }
        __syncthreads();
        if (t == 0) {
            wsF[b] = fminf(fminf(sm[0], sm[1]), fminf(sm[2], sm[3]));
            wsF[2048 + b] = fmaxf(fmaxf(sM[0], sM[1]), fmaxf(sM[2], sM[3]));
            if (b == 0) {
                wsF[WS_SUM] = 0.f;
                wsF[WS_CNT] = 0.f;
                ((unsigned*)wsF)[WS_TKT] = 0u;
            }
        }
    }
}

// Pass 2: 2-wave (128-thr) block = half-row band (4 output rows, 2 per wave).
// All 12 target rows staged ONCE in the prologue into compact 4352-B slots
// (waves split 6/6); one vmcnt(0)+barrier; then pure compute with direct slot
// indexing -- no ring wrap, no restaging, no mid-loop drains.
// Codegen ledger: compiler waves/EU estimate = floor(LDS-blocks/CU * waves/blk
// / 4). Estimate 1 -> relaxed schedule (R0: 132 VGPR, fast). Estimate >=3 ->
// pressure-crushed (R1/R3: 76 VGPR even with budget 170). Here: 52.2 KB -> 3
// blocks/CU * 2 waves / 4 EU = 1.5 -> floors to 1 -> relaxed, while HARDWARE
// residency doubles vs R0 (6 waves/CU). Inner loop byte-identical to R0/R1.
__global__ __launch_bounds__(128) void k_main(const float* __restrict__ ms,
                                              const uint4* __restrict__ qt4,
                                              float* __restrict__ wsF,
                                              const uint* __restrict__ dv16,
                                              float* __restrict__ out) {
    __shared__ __align__(16) uint ldsU[NSLOT * SLOTC]; // 52224 B -> 3 blocks/CU
    __shared__ float sS[2], sC[2];
    const int t = threadIdx.x & 63;   // lane
    const int wv = threadIdx.x >> 6;  // wave 0/1
    const int b = blockIdx.x;         // 0..1023
    const int xcd = b & 7;
    const int q = b >> 3;             // 0..127
    const int n = q >> 6;
    const int r = q & 63;
    const int hb = r >> 5;
    const int w = r & 31;
    const int h0 = xcd * 128 + 16 * (w >> 2) + (w & 3);
    const int w0 = hb * 512 + 8 * t;

    // ---- mask min/max loads first (their waitcnt won't drain stage DMA) ----
    float lmin = 1.0e38f, lmax = -1.0e38f;
#pragma unroll
    for (int k = 0; k < 8; ++k) {
        float4 v = ((const float4*)wsF)[k * 64 + t];
        float4 x = ((const float4*)(wsF + 2048))[k * 64 + t];
        lmin = fminf(lmin, fminf(fminf(v.x, v.y), fminf(v.z, v.w)));
        lmax = fmaxf(lmax, fmaxf(fmaxf(x.x, x.y), fmaxf(x.z, x.w)));
    }

    // ---- prologue: stage all 12 slots, wave wv stages slots 6*wv..6*wv+5 ----
    const size_t nBase = ((size_t)n << 10);
#pragma unroll 1
    for (int i = 0; i < 6; ++i) {
        int s = 6 * wv + i;
        int row = reflect_idx(h0 + 4 * (s - 4));
        const uint* rec = (const uint*)(qt4 + ((nBase + row) * 2 + hb) * RECU4);
#pragma unroll
        for (int c = 0; c < 4; ++c)
            GLD16(rec + c * 256 + 4 * t, &ldsU[s * SLOTC + c * 256]);
        if (t < 16)  // 256-B record tail: lanes 0..15 only (exec-masked DMA)
            GLD16(rec + 1024 + 4 * t, &ldsU[s * SLOTC + 1024]);
    }

#pragma unroll
    for (int off = 32; off > 0; off >>= 1) {
        lmin = fminf(lmin, __shfl_xor(lmin, off));
        lmax = fmaxf(lmax, __shfl_xor(lmax, off));
    }
    const float thresh = lmin + (lmax - lmin) * (10.0f / 255.0f);
    const float inv16 = 1.0f / 65535.0f;
    const float inv8 = 1.0f / 255.0f;

    asm volatile("s_waitcnt vmcnt(0)" ::: "memory");
    __syncthreads();   // all 12 slots visible to both waves

    float lsum = 0.f, lcnt = 0.f;

#pragma unroll 1
    for (int ko = 0; ko < 2; ++ko) {
        const int k = 2 * wv + ko;
        const int oh = h0 + 4 * k;

        // ms fragment: 8 px x 8 ch -> msq[2][8] (u8-packed), loads issued first
        const float* msBase = ms + (size_t)n * CHW + (size_t)oh * WW + w0;
        float4 A[2][4][2];
#pragma unroll
        for (int p = 0; p < 2; ++p)
#pragma unroll
            for (int cc = 0; cc < 4; ++cc) {
                A[p][cc][0] = *(const float4*)(msBase + (size_t)(4 * p + cc) * HWSZ);
                A[p][cc][1] = *(const float4*)(msBase + (size_t)(4 * p + cc) * HWSZ + 4);
            }
        uint4 dq = *(const uint4*)(dv16 + (((size_t)n * HWSZ + (size_t)oh * WW + w0) >> 1));

        uint msq[2][8];
#pragma unroll
        for (int p = 0; p < 2; ++p) {
#pragma unroll
            for (int half = 0; half < 2; ++half) {
                float4 c0 = A[p][0][half], c1 = A[p][1][half],
                       c2 = A[p][2][half], c3 = A[p][3][half];
                msq[p][4 * half + 0] = q8(c0.x) | (q8(c1.x) << 8) | (q8(c2.x) << 16) | (q8(c3.x) << 24);
                msq[p][4 * half + 1] = q8(c0.y) | (q8(c1.y) << 8) | (q8(c2.y) << 16) | (q8(c3.y) << 24);
                msq[p][4 * half + 2] = q8(c0.z) | (q8(c1.z) << 8) | (q8(c2.z) << 16) | (q8(c3.z) << 24);
                msq[p][4 * half + 3] = q8(c0.w) | (q8(c1.w) << 8) | (q8(c2.w) << 16) | (q8(c3.w) << 24);
            }
        }

        uint minv[8];
#pragma unroll
        for (int p = 0; p < 8; ++p) minv[p] = 0xffffffffu;

#pragma unroll 1
        for (int di = 0; di < 9; ++di) {
            const uint* sb = &ldsU[(k + di) * SLOTC];   // direct index, 0..11
            // 40-px windows, all reads independent (burst): E slots t..t+4, O likewise
            uint4 winE[2][5], winO[2][5];
#pragma unroll
            for (int p = 0; p < 2; ++p)
#pragma unroll
                for (int qq = 0; qq < 5; ++qq) {
                    winE[p][qq] = *(const uint4*)(sb + p * 544 + 4 * (t + qq));
                    winO[p][qq] = *(const uint4*)(sb + p * 544 + 272 + 4 * (t + qq));
                }
            uint acc[8];
#pragma unroll
            for (int dj = 0; dj < 9; ++dj) {
#pragma unroll
                for (int p = 0; p < 8; ++p) acc[p] = 0;
#pragma unroll
                for (int p = 0; p < 2; ++p) {
                    uint4 lo = (dj & 1) ? winO[p][(dj - 1) >> 1] : winE[p][dj >> 1];
                    uint4 hi = (dj & 1) ? winE[p][(dj + 1) >> 1] : winO[p][dj >> 1];
                    acc[0] = sadu8(msq[p][0], lo.x, acc[0]);
                    acc[1] = sadu8(msq[p][1], lo.y, acc[1]);
                    acc[2] = sadu8(msq[p][2], lo.z, acc[2]);
                    acc[3] = sadu8(msq[p][3], lo.w, acc[3]);
                    acc[4] = sadu8(msq[p][4], hi.x, acc[4]);
                    acc[5] = sadu8(msq[p][5], hi.y, acc[5]);
                    acc[6] = sadu8(msq[p][6], hi.z, acc[6]);
                    acc[7] = sadu8(msq[p][7], hi.w, acc[7]);
                }
#pragma unroll
                for (int p = 0; p < 8; ++p) minv[p] = min(minv[p], acc[p]);
            }
        }

        // masked accumulate for this output row
        uint dw[4] = {dq.x, dq.y, dq.z, dq.w};
#pragma unroll
        for (int p = 0; p < 4; ++p) {
            float d0 = (float)(dw[p] & 0xffffu) * inv16;
            float d1 = (float)(dw[p] >> 16) * inv16;
            if (d0 > thresh) { lsum += (float)minv[2 * p] * inv8; lcnt += 1.f; }
            if (d1 > thresh) { lsum += (float)minv[2 * p + 1] * inv8; lcnt += 1.f; }
        }
    }

#pragma unroll
    for (int off = 32; off > 0; off >>= 1) {
        lsum += __shfl_down(lsum, off);
        lcnt += __shfl_down(lcnt, off);
    }
    if (t == 0) { sS[wv] = lsum; sC[wv] = lcnt; }
    __syncthreads();
    if (threadIdx.x == 0) {
        atomicAdd(&wsF[WS_SUM], sS[0] + sS[1]);
        atomicAdd(&wsF[WS_CNT], sC[0] + sC[1]);
        __threadfence();
        unsigned tk = atomicAdd((unsigned*)&wsF[WS_TKT], 1u);
        if (tk == NBLK_MAIN - 1) {
            float s = atomicAdd(&wsF[WS_SUM], 0.f);
            float c = atomicAdd(&wsF[WS_CNT], 0.f);
            out[0] = (c > 0.f) ? (s / fmaxf(c, 1.f)) : 0.f;
        }
    }
}

extern "C" void kernel_launch(void* const* d_in, const int* in_sizes, int n_in,
                              void* d_out, int out_size, void* d_ws, size_t ws_size,
                              hipStream_t stream) {
    const float* ms  = (const float*)d_in[0];
    const float* tgt = (const float*)d_in[1];
    const float* msO = (const float*)d_in[2];
    const float* pan = (const float*)d_in[3];
    float* out = (float*)d_out;
    float* wsF = (float*)d_ws;
    uint* dv16 = (uint*)d_ws + WS_DV16;
    uint4* qt4 = (uint4*)((uint*)d_ws + WS_QT);

    k_pre<<<6144, 256, 0, stream>>>(tgt, qt4, msO, pan, wsF, dv16);
    k_main<<<NBLK_MAIN, 128, 0, stream>>>(ms, qt4, wsF, dv16, out);
}